// Round 1
// baseline (760.088 us; speedup 1.0000x reference)
//
#include <hip/hip_runtime.h>
#include <math.h>

#define CHN 256
#define C2N 256
#define HWSZ 4096

// ---------------- k1: dilated 3x3 offset conv + bias + clip/sigmoid ----------------
__global__ __launch_bounds__(256) void k1_offconv(const float* __restrict__ x,
    const float* __restrict__ w_off, const float* __restrict__ b_off,
    float* __restrict__ offs, float* __restrict__ mk)
{
    const int bh = blockIdx.x;
    const int b = bh >> 6, h = bh & 63;
    const int t = threadIdx.x;
    const int w = t & 63, ocq = t >> 6;          // 4 oc-phases per thread column
    __shared__ float xt[32][3][68];              // 32 channels x 3 rows x 68 cols
    float acc[7];
#pragma unroll
    for (int m = 0; m < 7; ++m) acc[m] = 0.f;
    const float* xb = x + b * CHN * HWSZ;
    for (int c0 = 0; c0 < CHN; c0 += 32) {
        __syncthreads();
        for (int e = t; e < 32 * 204; e += 256) {
            int cc = e / 204, rem = e - cc * 204;
            int r = rem / 68, col = rem - r * 68;
            int row = h + 2 * (r - 1), wc = col - 2;
            float v = 0.f;
            if ((unsigned)row < 64u && (unsigned)wc < 64u)
                v = xb[(c0 + cc) * HWSZ + row * 64 + wc];
            xt[cc][r][col] = v;
        }
        __syncthreads();
        for (int cc = 0; cc < 32; ++cc) {
            float xv[9];
#pragma unroll
            for (int i = 0; i < 3; ++i)
#pragma unroll
                for (int j = 0; j < 3; ++j)
                    xv[i * 3 + j] = xt[cc][i][w + 2 * j];
            const int c = c0 + cc;
#pragma unroll
            for (int m = 0; m < 7; ++m) {
                const int oc = ocq + 4 * m;
                if (oc < 27) {
                    const float* wr = w_off + (oc * CHN + c) * 9;
#pragma unroll
                    for (int k = 0; k < 9; ++k) acc[m] = fmaf(xv[k], wr[k], acc[m]);
                }
            }
        }
    }
#pragma unroll
    for (int m = 0; m < 7; ++m) {
        const int oc = ocq + 4 * m;
        if (oc < 27) {
            float v = acc[m] + b_off[oc];
            if (oc < 18) {
                v = fminf(fmaxf(v, -64.f), 64.f);
                offs[((b * 18 + oc) * 64 + h) * 64 + w] = v;
            } else {
                mk[((b * 9 + (oc - 18)) * 64 + h) * 64 + w] = 1.f / (1.f + expf(-v));
            }
        }
    }
}

// ---------------- k2: fused deformable sampling + GEMM ----------------
// block = (b,h) row x M-half (128 d's). 256 threads: tx in 0..7 (w0=tx*8), ty in 0..31 (d0=ty*4).
__global__ __launch_bounds__(256) void k2_dcn(const float* __restrict__ x,
    const float* __restrict__ w_dcn, const float* __restrict__ offs,
    const float* __restrict__ mk, float* __restrict__ out)
{
    const int bid = blockIdx.x;
    const int bh = bid & 255;
    const int mblk = bid >> 8;                 // 0/1
    const int b = bh >> 6, h = bh & 63;
    const int t = threadIdx.x;
    const int tx = t & 7, ty = t >> 3;
    const int w0 = tx * 8;
    const int d0 = mblk * 128 + ty * 4;

    __shared__ __align__(16) int4   sidx[576];   // per (k,w): 4 corner indices
    __shared__ __align__(16) float4 swgt[576];   // per (k,w): mask-premult bilinear weights
    __shared__ __align__(16) float  samp[36][64];
    __shared__ __align__(16) float  wl[36][128];

    // phase 0: sampling metadata for 9 taps x 64 w
    for (int e = t; e < 576; e += 256) {
        const int k = e >> 6, ww = e & 63;
        const float dy = offs[((b * 18 + 2 * k)     * 64 + h) * 64 + ww];
        const float dx = offs[((b * 18 + 2 * k + 1) * 64 + h) * 64 + ww];
        const float m  = mk  [((b * 9 + k)          * 64 + h) * 64 + ww];
        const float py = (float)(h - 1 + k / 3) + dy;
        const float px = (float)(ww - 1 + k % 3) + dx;
        const float y0f = floorf(py), x0f = floorf(px);
        const float wy = py - y0f, wx = px - x0f;
        const int y0 = (int)y0f, x0 = (int)x0f;
        float w00 = (1.f - wy) * (1.f - wx) * m, w01 = (1.f - wy) * wx * m;
        float w10 = wy * (1.f - wx) * m,         w11 = wy * wx * m;
        const bool vy0 = (unsigned)y0 < 64u, vy1 = (unsigned)(y0 + 1) < 64u;
        const bool vx0 = (unsigned)x0 < 64u, vx1 = (unsigned)(x0 + 1) < 64u;
        if (!(vy0 && vx0)) w00 = 0.f;
        if (!(vy0 && vx1)) w01 = 0.f;
        if (!(vy1 && vx0)) w10 = 0.f;
        if (!(vy1 && vx1)) w11 = 0.f;
        const int y0c = min(max(y0, 0), 63), y1c = min(max(y0 + 1, 0), 63);
        const int x0c = min(max(x0, 0), 63), x1c = min(max(x0 + 1, 0), 63);
        sidx[e] = make_int4(y0c * 64 + x0c, y0c * 64 + x1c, y1c * 64 + x0c, y1c * 64 + x1c);
        swgt[e] = make_float4(w00, w01, w10, w11);
    }

    float acc[4][8];
#pragma unroll
    for (int i = 0; i < 4; ++i)
#pragma unroll
        for (int j = 0; j < 8; ++j) acc[i][j] = 0.f;

    const float* xb = x + b * CHN * HWSZ;
    const int dd = t >> 1, halfu = (t & 1) * 18;

    for (int c0 = 0; c0 < CHN; c0 += 4) {
        __syncthreads();
        // stage samp[cl*9+k][w] for 4 channels
        for (int e = t; e < 2304; e += 256) {
            const int ck = e >> 6, ww = e & 63;
            const int cl = ck / 9, k = ck - cl * 9;
            const float* xc = xb + (c0 + cl) * HWSZ;
            const int me = k * 64 + ww;
            const int4 id = sidx[me];
            const float4 wt = swgt[me];
            samp[ck][ww] = wt.x * xc[id.x] + wt.y * xc[id.y] + wt.z * xc[id.z] + wt.w * xc[id.w];
        }
        // stage w_dcn transposed: wl[cl*9+k][d]
        {
            const float* wr = w_dcn + ((mblk * 128 + dd) * CHN + c0) * 9 + halfu;
#pragma unroll
            for (int u = 0; u < 18; ++u) wl[halfu + u][dd] = wr[u];
        }
        __syncthreads();
#pragma unroll 6
        for (int kk = 0; kk < 36; ++kk) {
            const float4 a  = *(const float4*)&wl[kk][ty * 4];
            const float4 b0 = *(const float4*)&samp[kk][w0];
            const float4 b1 = *(const float4*)&samp[kk][w0 + 4];
            const float av[4] = {a.x, a.y, a.z, a.w};
            const float bv[8] = {b0.x, b0.y, b0.z, b0.w, b1.x, b1.y, b1.z, b1.w};
#pragma unroll
            for (int i = 0; i < 4; ++i)
#pragma unroll
                for (int j = 0; j < 8; ++j) acc[i][j] = fmaf(av[i], bv[j], acc[i][j]);
        }
    }
#pragma unroll
    for (int i = 0; i < 4; ++i) {
        float* op = out + ((b * C2N + d0 + i) * 64 + h) * 64 + w0;
        *(float4*)op       = make_float4(acc[i][0], acc[i][1], acc[i][2], acc[i][3]);
        *(float4*)(op + 4) = make_float4(acc[i][4], acc[i][5], acc[i][6], acc[i][7]);
    }
}

// ---------------- k3: GroupNorm stats per (b,g) ----------------
__global__ __launch_bounds__(256) void k3_stats(const float* __restrict__ out, float* __restrict__ stats)
{
    const int bg = blockIdx.x;                   // b*32+g; group data contiguous: 32768 floats
    const float* p = out + (size_t)bg * 32768;
    float s = 0.f, s2 = 0.f;
    for (int i = threadIdx.x; i < 8192; i += 256) {
        float4 v = ((const float4*)p)[i];
        s  += v.x + v.y + v.z + v.w;
        s2 += v.x * v.x + v.y * v.y + v.z * v.z + v.w * v.w;
    }
    __shared__ float r1[256], r2[256];
    r1[threadIdx.x] = s; r2[threadIdx.x] = s2;
    __syncthreads();
    for (int st = 128; st > 0; st >>= 1) {
        if (threadIdx.x < st) {
            r1[threadIdx.x] += r1[threadIdx.x + st];
            r2[threadIdx.x] += r2[threadIdx.x + st];
        }
        __syncthreads();
    }
    if (threadIdx.x == 0) {
        float mean = r1[0] / 32768.f;
        float var  = r2[0] / 32768.f - mean * mean;
        stats[bg * 2]     = mean;
        stats[bg * 2 + 1] = rsqrtf(var + 1e-5f);
    }
}

// ---------------- k4: normalize + affine + SiLU, in place ----------------
__global__ __launch_bounds__(256) void k4_gn(float* __restrict__ out,
    const float* __restrict__ stats, const float* __restrict__ gamma, const float* __restrict__ beta)
{
    const int i4 = blockIdx.x * 256 + threadIdx.x;   // float4 index, 1048576 total
    const int elem = i4 << 2;
    const int b = elem >> 20;
    const int ch = (elem >> 12) & 255;
    const int g = ch >> 3;
    const float mean = stats[(b * 32 + g) * 2];
    const float rstd = stats[(b * 32 + g) * 2 + 1];
    const float ga = gamma[ch], be = beta[ch];
    float4 v = ((float4*)out)[i4];
    float vv[4] = {v.x, v.y, v.z, v.w};
#pragma unroll
    for (int j = 0; j < 4; ++j) {
        float o = (vv[j] - mean) * rstd * ga + be;
        vv[j] = o / (1.f + expf(-o));
    }
    ((float4*)out)[i4] = make_float4(vv[0], vv[1], vv[2], vv[3]);
}

extern "C" void kernel_launch(void* const* d_in, const int* in_sizes, int n_in,
                              void* d_out, int out_size, void* d_ws, size_t ws_size,
                              hipStream_t stream)
{
    const float* x     = (const float*)d_in[0];
    const float* w_off = (const float*)d_in[1];
    const float* b_off = (const float*)d_in[2];
    const float* w_dcn = (const float*)d_in[3];
    const float* gamma = (const float*)d_in[4];
    const float* beta  = (const float*)d_in[5];
    float* out   = (float*)d_out;
    float* offs  = (float*)d_ws;                    // 4*18*4096 floats
    float* mk    = offs + 4 * 18 * 4096;            // 4*9*4096 floats
    float* stats = mk + 4 * 9 * 4096;               // 256 floats

    hipLaunchKernelGGL(k1_offconv, dim3(256),  dim3(256), 0, stream, x, w_off, b_off, offs, mk);
    hipLaunchKernelGGL(k2_dcn,     dim3(512),  dim3(256), 0, stream, x, w_dcn, offs, mk, out);
    hipLaunchKernelGGL(k3_stats,   dim3(128),  dim3(256), 0, stream, out, stats);
    hipLaunchKernelGGL(k4_gn,      dim3(4096), dim3(256), 0, stream, out, stats, gamma, beta);
}

// Round 2
// 275.615 us; speedup vs baseline: 2.7578x; 2.7578x over previous
//
#include <hip/hip_runtime.h>
#include <math.h>

#define HW 4096

typedef __attribute__((ext_vector_type(8))) short short8;
typedef __attribute__((ext_vector_type(4))) float f32x4;

static __device__ inline ushort f2bf(float f) {
    uint u = __builtin_bit_cast(uint, f);
    uint r = (u + 0x7fffu + ((u >> 16) & 1u)) >> 16;
    return (ushort)r;
}

// ---------------- k0: x [b][c][h][w] f32 -> x_t [b][h][w][c] bf16 ----------------
__global__ __launch_bounds__(256) void k0_xt(const float* __restrict__ x, ushort* __restrict__ xt)
{
    const int blk = blockIdx.x;              // b*64 + h
    const int b = blk >> 6, h = blk & 63;
    __shared__ ushort tile[64 * 258];        // row pad 258 -> conflict-free
    const float* xb = x + ((size_t)b * 256) * HW + h * 64;
    const int t = threadIdx.x;
    for (int e = t; e < 16384; e += 256) {
        const int c = e >> 6, j = e & 63;
        tile[j * 258 + c] = f2bf(xb[c * HW + j]);
    }
    __syncthreads();
    uint* xo = (uint*)(xt + ((size_t)b * HW + h * 64) * 256);
    for (int e = t; e < 8192; e += 256) {
        const int j = e >> 7, q = e & 127;
        const uint u = *(const uint*)&tile[j * 258 + 2 * q];
        xo[j * 128 + q] = u;
    }
}

// ---------------- k0w: w_dcn [d][c][3][3] f32 -> wT [k][d][c] bf16 ----------------
__global__ __launch_bounds__(256) void k0_wt(const float* __restrict__ w_dcn, ushort* __restrict__ wT)
{
    const int e = blockIdx.x * 256 + threadIdx.x;   // 589824
    const int k = e >> 16, d = (e >> 8) & 255, c = e & 255;
    wT[e] = f2bf(w_dcn[(d * 256 + c) * 9 + k]);
}

// ---------------- k1: dilated 3x3 offset conv, partial over c-halves ----------------
__global__ __launch_bounds__(512) void k1_offconv(const float* __restrict__ x,
    const float* __restrict__ w_off, float* __restrict__ part)
{
    const int bid = blockIdx.x;              // s*256 + b*64 + h
    const int s = bid >> 8, bh = bid & 255;
    const int b = bh >> 6, h = bh & 63;
    const int t = threadIdx.x;
    const int w = t & 63, ocq = t >> 6;      // ocq 0..7
    __shared__ float xtile[32][3][68];
    __shared__ float wl[27 * 288];           // [oc][cc*9+k]
    float acc[4] = {0.f, 0.f, 0.f, 0.f};
    const float* xb = x + ((size_t)b * 256) * HW;
    const int cbase = s * 128;
    for (int c0 = cbase; c0 < cbase + 128; c0 += 32) {
        __syncthreads();
        for (int e = t; e < 32 * 204; e += 512) {
            const int cc = e / 204, rem = e - cc * 204;
            const int r = rem / 68, col = rem - r * 68;
            const int row = h + 2 * (r - 1), wc = col - 2;
            float v = 0.f;
            if ((unsigned)row < 64u && (unsigned)wc < 64u)
                v = xb[(c0 + cc) * HW + row * 64 + wc];
            xtile[cc][r][col] = v;
        }
        for (int e = t; e < 27 * 288; e += 512) {
            const int oc = e / 288, r = e - oc * 288;
            wl[e] = w_off[oc * 2304 + c0 * 9 + r];
        }
        __syncthreads();
        for (int cc = 0; cc < 32; ++cc) {
            float xv[9];
#pragma unroll
            for (int i = 0; i < 3; ++i)
#pragma unroll
                for (int j = 0; j < 3; ++j)
                    xv[i * 3 + j] = xtile[cc][i][w + 2 * j];
#pragma unroll
            for (int m = 0; m < 4; ++m) {
                const int oc = ocq + 8 * m;
                if (oc < 27) {
                    const float* wr = &wl[oc * 288 + cc * 9];
#pragma unroll
                    for (int k = 0; k < 9; ++k) acc[m] = fmaf(xv[k], wr[k], acc[m]);
                }
            }
        }
    }
#pragma unroll
    for (int m = 0; m < 4; ++m) {
        const int oc = ocq + 8 * m;
        if (oc < 27)
            part[((size_t)(s * 27 + oc) * 4 + b) * HW + h * 64 + w] = acc[m];
    }
}

// ---------------- k1b: reduce halves + bias + clip/sigmoid ----------------
__global__ __launch_bounds__(256) void k1b(const float* __restrict__ part, const float* __restrict__ b_off,
    float* __restrict__ offs, float* __restrict__ mk)
{
    const int e = blockIdx.x * 256 + threadIdx.x;    // 27*4*4096 = 442368
    const int oc = e / 16384, r = e & 16383;
    const int b = r >> 12, hw = r & 4095;
    float v = part[e] + part[442368 + e] + b_off[oc];
    if (oc < 18) {
        v = fminf(fmaxf(v, -64.f), 64.f);
        offs[(b * 18 + oc) * HW + hw] = v;
    } else {
        mk[(b * 9 + (oc - 18)) * HW + hw] = 1.f / (1.f + expf(-v));
    }
}

// ---------------- k2: fused sampling + MFMA GEMM ----------------
// block = one (b,h) row; 1024 threads = 16 waves; wave wd owns d rows [wd*16, wd*16+16)
__global__ __launch_bounds__(1024) void k2_dcn(const ushort* __restrict__ xt, const ushort* __restrict__ wT,
    const float* __restrict__ offs, const float* __restrict__ mk, float* __restrict__ out)
{
    const int bid = blockIdx.x;
    const int wg = (bid & 7) * 32 + (bid >> 3);      // XCD-bijective swizzle (256 = 8*32)
    const int b = wg >> 6, h = wg & 63;
    const int t = threadIdx.x;

    __shared__ int4   cOff[576];                     // byte offsets of 4 corners into x_t[b]
    __shared__ float4 cWgt[576];                     // mask-premult bilinear weights
    __shared__ ushort Alds[256 * 40];                // wT chunk [d][32c], rows padded to 40 el (80B)
    __shared__ ushort Slds[64 * 40];                 // samp chunk [w][32c], rows padded to 40 el

    if (t < 576) {
        const int k = t >> 6, ww = t & 63;
        const float dy = offs[(b * 18 + 2 * k) * HW + h * 64 + ww];
        const float dx = offs[(b * 18 + 2 * k + 1) * HW + h * 64 + ww];
        const float mval = mk[(b * 9 + k) * HW + h * 64 + ww];
        const float py = (float)(h - 1 + k / 3) + dy;
        const float px = (float)(ww - 1 + k % 3) + dx;
        const float y0f = floorf(py), x0f = floorf(px);
        const float wy = py - y0f, wx = px - x0f;
        const int y0 = (int)y0f, x0 = (int)x0f;
        float w00 = (1.f - wy) * (1.f - wx) * mval, w01 = (1.f - wy) * wx * mval;
        float w10 = wy * (1.f - wx) * mval,         w11 = wy * wx * mval;
        const bool vy0 = (unsigned)y0 < 64u, vy1 = (unsigned)(y0 + 1) < 64u;
        const bool vx0 = (unsigned)x0 < 64u, vx1 = (unsigned)(x0 + 1) < 64u;
        if (!(vy0 && vx0)) w00 = 0.f;
        if (!(vy0 && vx1)) w01 = 0.f;
        if (!(vy1 && vx0)) w10 = 0.f;
        if (!(vy1 && vx1)) w11 = 0.f;
        const int y0c = min(max(y0, 0), 63), y1c = min(max(y0 + 1, 0), 63);
        const int x0c = min(max(x0, 0), 63), x1c = min(max(x0 + 1, 0), 63);
        cOff[t] = make_int4((y0c * 64 + x0c) * 512, (y0c * 64 + x1c) * 512,
                            (y1c * 64 + x0c) * 512, (y1c * 64 + x1c) * 512);
        cWgt[t] = make_float4(w00, w01, w10, w11);
    }

    f32x4 acc[4];
#pragma unroll
    for (int nf = 0; nf < 4; ++nf) acc[nf] = (f32x4){0.f, 0.f, 0.f, 0.f};

    const char* xc = (const char*)(xt + ((size_t)b * HW) * 256);
    const int lane = t & 63;
    const int d0 = (t >> 6) * 16;
    const int n0 = lane & 15, kb = (lane >> 4) * 8;
    const int sd = t >> 2, sq = t & 3;               // A-stage mapping
    const int sw = t >> 4, sp = t & 15;              // samp-stage mapping

    __syncthreads();                                 // meta ready

    for (int k = 0; k < 9; ++k) {
        const int4   co = cOff[k * 64 + sw];
        const float4 cw = cWgt[k * 64 + sw];
        for (int c0 = 0; c0 < 256; c0 += 32) {
            __syncthreads();                         // previous chunk's reads done
            {   // stage A: 256x32 bf16, coalesced 16B per thread
                const short8 av = *(const short8*)(wT + ((k * 256 + sd) * 256 + c0 + sq * 8));
                *(short8*)(&Alds[sd * 40 + sq * 8]) = av;
            }
            {   // stage samp: 2 channels per thread (one dword per corner)
                const int cb = (c0 + sp * 2) * 2;
                const uint u00 = *(const uint*)(xc + (co.x + cb));
                const uint u01 = *(const uint*)(xc + (co.y + cb));
                const uint u10 = *(const uint*)(xc + (co.z + cb));
                const uint u11 = *(const uint*)(xc + (co.w + cb));
                const float sa = cw.x * __builtin_bit_cast(float, u00 << 16)
                               + cw.y * __builtin_bit_cast(float, u01 << 16)
                               + cw.z * __builtin_bit_cast(float, u10 << 16)
                               + cw.w * __builtin_bit_cast(float, u11 << 16);
                const float sb = cw.x * __builtin_bit_cast(float, u00 & 0xffff0000u)
                               + cw.y * __builtin_bit_cast(float, u01 & 0xffff0000u)
                               + cw.z * __builtin_bit_cast(float, u10 & 0xffff0000u)
                               + cw.w * __builtin_bit_cast(float, u11 & 0xffff0000u);
                ((uint*)Slds)[sw * 20 + sp] = (uint)f2bf(sa) | ((uint)f2bf(sb) << 16);
            }
            __syncthreads();
            const short8 af = *(const short8*)(&Alds[(d0 + n0) * 40 + kb]);
#pragma unroll
            for (int nf = 0; nf < 4; ++nf) {
                const short8 bf = *(const short8*)(&Slds[(nf * 16 + n0) * 40 + kb]);
                acc[nf] = __builtin_amdgcn_mfma_f32_16x16x32_bf16(af, bf, acc[nf], 0, 0, 0);
            }
        }
    }

    float* ob = out + ((size_t)b * 256) * HW + h * 64;
#pragma unroll
    for (int nf = 0; nf < 4; ++nf)
#pragma unroll
        for (int r = 0; r < 4; ++r) {
            const int d = d0 + (lane >> 4) * 4 + r;
            ob[d * HW + nf * 16 + n0] = acc[nf][r];
        }
}

// ---------------- k3: GroupNorm stats per (b,g) ----------------
__global__ __launch_bounds__(256) void k3_stats(const float* __restrict__ out, float* __restrict__ stats)
{
    const int bg = blockIdx.x;
    const float* p = out + (size_t)bg * 32768;
    float s = 0.f, s2 = 0.f;
    for (int i = threadIdx.x; i < 8192; i += 256) {
        float4 v = ((const float4*)p)[i];
        s  += v.x + v.y + v.z + v.w;
        s2 += v.x * v.x + v.y * v.y + v.z * v.z + v.w * v.w;
    }
    __shared__ float r1[256], r2[256];
    r1[threadIdx.x] = s; r2[threadIdx.x] = s2;
    __syncthreads();
    for (int st = 128; st > 0; st >>= 1) {
        if (threadIdx.x < st) {
            r1[threadIdx.x] += r1[threadIdx.x + st];
            r2[threadIdx.x] += r2[threadIdx.x + st];
        }
        __syncthreads();
    }
    if (threadIdx.x == 0) {
        const float mean = r1[0] / 32768.f;
        const float var  = r2[0] / 32768.f - mean * mean;
        stats[bg * 2]     = mean;
        stats[bg * 2 + 1] = rsqrtf(var + 1e-5f);
    }
}

// ---------------- k4: normalize + affine + SiLU ----------------
__global__ __launch_bounds__(256) void k4_gn(float* __restrict__ out,
    const float* __restrict__ stats, const float* __restrict__ gamma, const float* __restrict__ beta)
{
    const int i4 = blockIdx.x * 256 + threadIdx.x;
    const int elem = i4 << 2;
    const int b = elem >> 20;
    const int ch = (elem >> 12) & 255;
    const int g = ch >> 3;
    const float mean = stats[(b * 32 + g) * 2];
    const float rstd = stats[(b * 32 + g) * 2 + 1];
    const float ga = gamma[ch], be = beta[ch];
    float4 v = ((float4*)out)[i4];
    float vv[4] = {v.x, v.y, v.z, v.w};
#pragma unroll
    for (int j = 0; j < 4; ++j) {
        const float o = (vv[j] - mean) * rstd * ga + be;
        vv[j] = o / (1.f + expf(-o));
    }
    ((float4*)out)[i4] = make_float4(vv[0], vv[1], vv[2], vv[3]);
}

extern "C" void kernel_launch(void* const* d_in, const int* in_sizes, int n_in,
                              void* d_out, int out_size, void* d_ws, size_t ws_size,
                              hipStream_t stream)
{
    const float* x     = (const float*)d_in[0];
    const float* w_off = (const float*)d_in[1];
    const float* b_off = (const float*)d_in[2];
    const float* w_dcn = (const float*)d_in[3];
    const float* gamma = (const float*)d_in[4];
    const float* beta  = (const float*)d_in[5];
    float* out = (float*)d_out;

    // ws layout (floats). Region A (2097152 f) holds part (884736 f) first, then x_t bf16 overlays it.
    float*  part  = (float*)d_ws;
    ushort* xt    = (ushort*)d_ws;
    float*  offs  = (float*)d_ws + 2097152;
    float*  mk    = offs + 294912;
    float*  stats = mk + 147456;
    ushort* wT    = (ushort*)(stats + 256);

    hipLaunchKernelGGL(k1_offconv, dim3(512),  dim3(512),  0, stream, x, w_off, part);
    hipLaunchKernelGGL(k1b,        dim3(1728), dim3(256),  0, stream, part, b_off, offs, mk);
    hipLaunchKernelGGL(k0_xt,      dim3(256),  dim3(256),  0, stream, x, xt);     // overlays part (consumed)
    hipLaunchKernelGGL(k0_wt,      dim3(2304), dim3(256),  0, stream, w_dcn, wT);
    hipLaunchKernelGGL(k2_dcn,     dim3(256),  dim3(1024), 0, stream, xt, wT, offs, mk, out);
    hipLaunchKernelGGL(k3_stats,   dim3(128),  dim3(256),  0, stream, out, stats);
    hipLaunchKernelGGL(k4_gn,      dim3(4096), dim3(256),  0, stream, out, stats, gamma, beta);
}

// Round 3
// 209.932 us; speedup vs baseline: 3.6206x; 1.3129x over previous
//
#include <hip/hip_runtime.h>
#include <math.h>

#define HW 4096

typedef __attribute__((ext_vector_type(8))) short short8;
typedef __attribute__((ext_vector_type(4))) float f32x4;

static __device__ inline ushort f2bf(float f) {
    uint u = __builtin_bit_cast(uint, f);
    uint r = (u + 0x7fffu + ((u >> 16) & 1u)) >> 16;
    return (ushort)r;
}

// ---------------- k0: x [b][c][h][w] f32 -> x_t [b][h][w][c] bf16 ----------------
__global__ __launch_bounds__(256) void k0_xt(const float* __restrict__ x, ushort* __restrict__ xt)
{
    const int blk = blockIdx.x;              // b*64 + h
    const int b = blk >> 6, h = blk & 63;
    __shared__ ushort tile[64 * 258];
    const float* xb = x + ((size_t)b * 256) * HW + h * 64;
    const int t = threadIdx.x;
    for (int e = t; e < 16384; e += 256) {
        const int c = e >> 6, j = e & 63;
        tile[j * 258 + c] = f2bf(xb[c * HW + j]);
    }
    __syncthreads();
    uint* xo = (uint*)(xt + ((size_t)b * HW + h * 64) * 256);
    for (int e = t; e < 8192; e += 256) {
        const int j = e >> 7, q = e & 127;
        xo[j * 128 + q] = *(const uint*)&tile[j * 258 + 2 * q];
    }
}

// ---------------- k0w: w_dcn [d][c][3][3] f32 -> wT [k][d][c] bf16 ----------------
__global__ __launch_bounds__(256) void k0_wt(const float* __restrict__ w_dcn, ushort* __restrict__ wT)
{
    const int e = blockIdx.x * 256 + threadIdx.x;   // 589824
    const int k = e >> 16, d = (e >> 8) & 255, c = e & 255;
    wT[e] = f2bf(w_dcn[(d * 256 + c) * 9 + k]);
}

// ---------------- k0o: w_off [oc][c][3][3] f32 -> wA [tap][oc_pad32][c] bf16 ----------------
__global__ __launch_bounds__(256) void k0_wo(const float* __restrict__ w_off, ushort* __restrict__ wA)
{
    const int e = blockIdx.x * 256 + threadIdx.x;   // 9*32*256 = 73728
    const int k = e >> 13, r = e & 8191;
    const int oc = r >> 8, c = r & 255;
    const float v = (oc < 27) ? w_off[(oc * 256 + c) * 9 + k] : 0.f;
    wA[e] = f2bf(v);
}

// ---------------- k1: offset conv as LDS-free MFMA GEMM + bias/clip/sigmoid ----------------
// block = (b,h); 4 waves, wave wv owns w-cols [wv*16, wv*16+16); M=32 (27 used), K=9 taps x 256 c
__global__ __launch_bounds__(256) void k1_mfma(const ushort* __restrict__ xt,
    const ushort* __restrict__ wA, const float* __restrict__ b_off,
    float* __restrict__ offs, float* __restrict__ mk)
{
    const int bid = blockIdx.x;
    const int b = bid >> 6, h = bid & 63;
    const int t = threadIdx.x;
    const int lane = t & 63, wv = t >> 6;
    const int n = lane & 15, kq = lane >> 4;

    f32x4 acc0 = {0.f, 0.f, 0.f, 0.f}, acc1 = {0.f, 0.f, 0.f, 0.f};
    const ushort* xb = xt + ((size_t)b * HW) * 256;

    for (int k = 0; k < 9; ++k) {
        const int i = k / 3, j = k % 3;
        const int hh = h + 2 * (i - 1);
        if ((unsigned)hh >= 64u) continue;
        const int ww = wv * 16 + n + 2 * (j - 1);
        const bool vw = (unsigned)ww < 64u;
        const ushort* xrow  = xb + (hh * 64 + ww) * 256 + kq * 8;
        const ushort* wrow0 = wA + (k * 32 + n) * 256 + kq * 8;
        const ushort* wrow1 = wrow0 + 16 * 256;
#pragma unroll
        for (int c0 = 0; c0 < 256; c0 += 32) {
            short8 bfv = {0, 0, 0, 0, 0, 0, 0, 0};
            if (vw) bfv = *(const short8*)(xrow + c0);
            const short8 a0 = *(const short8*)(wrow0 + c0);
            const short8 a1 = *(const short8*)(wrow1 + c0);
            acc0 = __builtin_amdgcn_mfma_f32_16x16x32_bf16(a0, bfv, acc0, 0, 0, 0);
            acc1 = __builtin_amdgcn_mfma_f32_16x16x32_bf16(a1, bfv, acc1, 0, 0, 0);
        }
    }

    const int hw = h * 64 + wv * 16 + n;
#pragma unroll
    for (int r = 0; r < 4; ++r) {
        {   // acc0 rows: oc = kq*4 + r in 0..15, all offsets
            const int oc = kq * 4 + r;
            float v = acc0[r] + b_off[oc];
            v = fminf(fmaxf(v, -64.f), 64.f);
            offs[(b * 18 + oc) * HW + hw] = v;
        }
        {   // acc1 rows: oc = 16 + kq*4 + r in 16..31
            const int oc = 16 + kq * 4 + r;
            const float v = acc1[r] + b_off[min(oc, 26)];
            if (oc < 18) {
                offs[(b * 18 + oc) * HW + hw] = fminf(fmaxf(v, -64.f), 64.f);
            } else if (oc < 27) {
                mk[(b * 9 + (oc - 18)) * HW + hw] = 1.f / (1.f + expf(-v));
            }
        }
    }
}

// ---------------- k2: fused sampling + MFMA GEMM ----------------
__global__ __launch_bounds__(1024) void k2_dcn(const ushort* __restrict__ xt, const ushort* __restrict__ wT,
    const float* __restrict__ offs, const float* __restrict__ mk, float* __restrict__ out)
{
    const int bid = blockIdx.x;
    const int wg = (bid & 7) * 32 + (bid >> 3);      // XCD-bijective swizzle (256 = 8*32)
    const int b = wg >> 6, h = wg & 63;
    const int t = threadIdx.x;

    __shared__ int4   cOff[576];
    __shared__ float4 cWgt[576];
    __shared__ ushort Alds[256 * 40];
    __shared__ ushort Slds[64 * 40];

    if (t < 576) {
        const int k = t >> 6, ww = t & 63;
        const float dy = offs[(b * 18 + 2 * k) * HW + h * 64 + ww];
        const float dx = offs[(b * 18 + 2 * k + 1) * HW + h * 64 + ww];
        const float mval = mk[(b * 9 + k) * HW + h * 64 + ww];
        const float py = (float)(h - 1 + k / 3) + dy;
        const float px = (float)(ww - 1 + k % 3) + dx;
        const float y0f = floorf(py), x0f = floorf(px);
        const float wy = py - y0f, wx = px - x0f;
        const int y0 = (int)y0f, x0 = (int)x0f;
        float w00 = (1.f - wy) * (1.f - wx) * mval, w01 = (1.f - wy) * wx * mval;
        float w10 = wy * (1.f - wx) * mval,         w11 = wy * wx * mval;
        const bool vy0 = (unsigned)y0 < 64u, vy1 = (unsigned)(y0 + 1) < 64u;
        const bool vx0 = (unsigned)x0 < 64u, vx1 = (unsigned)(x0 + 1) < 64u;
        if (!(vy0 && vx0)) w00 = 0.f;
        if (!(vy0 && vx1)) w01 = 0.f;
        if (!(vy1 && vx0)) w10 = 0.f;
        if (!(vy1 && vx1)) w11 = 0.f;
        const int y0c = min(max(y0, 0), 63), y1c = min(max(y0 + 1, 0), 63);
        const int x0c = min(max(x0, 0), 63), x1c = min(max(x0 + 1, 0), 63);
        cOff[t] = make_int4((y0c * 64 + x0c) * 512, (y0c * 64 + x1c) * 512,
                            (y1c * 64 + x0c) * 512, (y1c * 64 + x1c) * 512);
        cWgt[t] = make_float4(w00, w01, w10, w11);
    }

    f32x4 acc[4];
#pragma unroll
    for (int nf = 0; nf < 4; ++nf) acc[nf] = (f32x4){0.f, 0.f, 0.f, 0.f};

    const char* xc = (const char*)(xt + ((size_t)b * HW) * 256);
    const int lane = t & 63;
    const int d0 = (t >> 6) * 16;
    const int n0 = lane & 15, kb = (lane >> 4) * 8;
    const int sd = t >> 2, sq = t & 3;
    const int sw = t >> 4, sp = t & 15;

    __syncthreads();

    for (int k = 0; k < 9; ++k) {
        const int4   co = cOff[k * 64 + sw];
        const float4 cw = cWgt[k * 64 + sw];
        for (int c0 = 0; c0 < 256; c0 += 32) {
            __syncthreads();
            {
                const short8 av = *(const short8*)(wT + ((k * 256 + sd) * 256 + c0 + sq * 8));
                *(short8*)(&Alds[sd * 40 + sq * 8]) = av;
            }
            {
                const int cb = (c0 + sp * 2) * 2;
                const uint u00 = *(const uint*)(xc + (co.x + cb));
                const uint u01 = *(const uint*)(xc + (co.y + cb));
                const uint u10 = *(const uint*)(xc + (co.z + cb));
                const uint u11 = *(const uint*)(xc + (co.w + cb));
                const float sa = cw.x * __builtin_bit_cast(float, u00 << 16)
                               + cw.y * __builtin_bit_cast(float, u01 << 16)
                               + cw.z * __builtin_bit_cast(float, u10 << 16)
                               + cw.w * __builtin_bit_cast(float, u11 << 16);
                const float sb = cw.x * __builtin_bit_cast(float, u00 & 0xffff0000u)
                               + cw.y * __builtin_bit_cast(float, u01 & 0xffff0000u)
                               + cw.z * __builtin_bit_cast(float, u10 & 0xffff0000u)
                               + cw.w * __builtin_bit_cast(float, u11 & 0xffff0000u);
                ((uint*)Slds)[sw * 20 + sp] = (uint)f2bf(sa) | ((uint)f2bf(sb) << 16);
            }
            __syncthreads();
            const short8 af = *(const short8*)(&Alds[(d0 + n0) * 40 + kb]);
#pragma unroll
            for (int nf = 0; nf < 4; ++nf) {
                const short8 bf = *(const short8*)(&Slds[(nf * 16 + n0) * 40 + kb]);
                acc[nf] = __builtin_amdgcn_mfma_f32_16x16x32_bf16(af, bf, acc[nf], 0, 0, 0);
            }
        }
    }

    float* ob = out + ((size_t)b * 256) * HW + h * 64;
#pragma unroll
    for (int nf = 0; nf < 4; ++nf)
#pragma unroll
        for (int r = 0; r < 4; ++r) {
            const int d = d0 + (lane >> 4) * 4 + r;
            ob[d * HW + nf * 16 + n0] = acc[nf][r];
        }
}

// ---------------- k3: GroupNorm stats per (b,g) ----------------
__global__ __launch_bounds__(256) void k3_stats(const float* __restrict__ out, float* __restrict__ stats)
{
    const int bg = blockIdx.x;
    const float* p = out + (size_t)bg * 32768;
    float s = 0.f, s2 = 0.f;
    for (int i = threadIdx.x; i < 8192; i += 256) {
        float4 v = ((const float4*)p)[i];
        s  += v.x + v.y + v.z + v.w;
        s2 += v.x * v.x + v.y * v.y + v.z * v.z + v.w * v.w;
    }
    __shared__ float r1[256], r2[256];
    r1[threadIdx.x] = s; r2[threadIdx.x] = s2;
    __syncthreads();
    for (int st = 128; st > 0; st >>= 1) {
        if (threadIdx.x < st) {
            r1[threadIdx.x] += r1[threadIdx.x + st];
            r2[threadIdx.x] += r2[threadIdx.x + st];
        }
        __syncthreads();
    }
    if (threadIdx.x == 0) {
        const float mean = r1[0] / 32768.f;
        const float var  = r2[0] / 32768.f - mean * mean;
        stats[bg * 2]     = mean;
        stats[bg * 2 + 1] = rsqrtf(var + 1e-5f);
    }
}

// ---------------- k4: normalize + affine + SiLU ----------------
__global__ __launch_bounds__(256) void k4_gn(float* __restrict__ out,
    const float* __restrict__ stats, const float* __restrict__ gamma, const float* __restrict__ beta)
{
    const int i4 = blockIdx.x * 256 + threadIdx.x;
    const int elem = i4 << 2;
    const int b = elem >> 20;
    const int ch = (elem >> 12) & 255;
    const int g = ch >> 3;
    const float mean = stats[(b * 32 + g) * 2];
    const float rstd = stats[(b * 32 + g) * 2 + 1];
    const float ga = gamma[ch], be = beta[ch];
    float4 v = ((float4*)out)[i4];
    float vv[4] = {v.x, v.y, v.z, v.w};
#pragma unroll
    for (int j = 0; j < 4; ++j) {
        const float o = (vv[j] - mean) * rstd * ga + be;
        vv[j] = o / (1.f + expf(-o));
    }
    ((float4*)out)[i4] = make_float4(vv[0], vv[1], vv[2], vv[3]);
}

extern "C" void kernel_launch(void* const* d_in, const int* in_sizes, int n_in,
                              void* d_out, int out_size, void* d_ws, size_t ws_size,
                              hipStream_t stream)
{
    const float* x     = (const float*)d_in[0];
    const float* w_off = (const float*)d_in[1];
    const float* b_off = (const float*)d_in[2];
    const float* w_dcn = (const float*)d_in[3];
    const float* gamma = (const float*)d_in[4];
    const float* beta  = (const float*)d_in[5];
    float* out = (float*)d_out;

    // ws layout: xt bf16 (8 MB) | offs | mk | stats | wT bf16 | wA bf16
    ushort* xt    = (ushort*)d_ws;
    float*  offs  = (float*)d_ws + 2097152;
    float*  mk    = offs + 294912;
    float*  stats = mk + 147456;
    ushort* wT    = (ushort*)(stats + 256);
    ushort* wA    = wT + 589824;

    hipLaunchKernelGGL(k0_xt,    dim3(256),  dim3(256),  0, stream, x, xt);
    hipLaunchKernelGGL(k0_wt,    dim3(2304), dim3(256),  0, stream, w_dcn, wT);
    hipLaunchKernelGGL(k0_wo,    dim3(288),  dim3(256),  0, stream, w_off, wA);
    hipLaunchKernelGGL(k1_mfma,  dim3(256),  dim3(256),  0, stream, xt, wA, b_off, offs, mk);
    hipLaunchKernelGGL(k2_dcn,   dim3(256),  dim3(1024), 0, stream, xt, wT, offs, mk, out);
    hipLaunchKernelGGL(k3_stats, dim3(128),  dim3(256),  0, stream, out, stats);
    hipLaunchKernelGGL(k4_gn,    dim3(4096), dim3(256),  0, stream, out, stats, gamma, beta);
}

// Round 4
// 195.907 us; speedup vs baseline: 3.8798x; 1.0716x over previous
//
#include <hip/hip_runtime.h>
#include <math.h>

#define HW 4096

typedef __attribute__((ext_vector_type(8))) short short8;
typedef __attribute__((ext_vector_type(4))) float f32x4;

static __device__ inline ushort f2bf(float f) {
    uint u = __builtin_bit_cast(uint, f);
    return (ushort)((u + 0x7fffu + ((u >> 16) & 1u)) >> 16);
}
static __device__ inline float bf2f(ushort s) {
    return __builtin_bit_cast(float, (uint)s << 16);
}

// ---------------- k0: x [b][c][h][w] f32 -> x_t [b][h][w][c] bf16 ----------------
__global__ __launch_bounds__(256) void k0_xt(const float* __restrict__ x, ushort* __restrict__ xt)
{
    const int blk = blockIdx.x;              // b*64 + h
    const int b = blk >> 6, h = blk & 63;
    __shared__ ushort tile[64 * 258];
    const float* xb = x + ((size_t)b * 256) * HW + h * 64;
    const int t = threadIdx.x;
    for (int e = t; e < 16384; e += 256) {
        const int c = e >> 6, j = e & 63;
        tile[j * 258 + c] = f2bf(xb[c * HW + j]);
    }
    __syncthreads();
    uint* xo = (uint*)(xt + ((size_t)b * HW + h * 64) * 256);
    for (int e = t; e < 8192; e += 256) {
        const int j = e >> 7, q = e & 127;
        xo[j * 128 + q] = *(const uint*)&tile[j * 258 + 2 * q];
    }
}

// ---------------- k0w: w_dcn [d][c][3][3] -> wT [k][d][c] bf16 (coalesced) ----------------
__global__ __launch_bounds__(256) void k0_wt(const float* __restrict__ w_dcn, ushort* __restrict__ wT)
{
    const int d = blockIdx.x;
    __shared__ float wl[2304];
    const int t = threadIdx.x;
    for (int i = t; i < 2304; i += 256) wl[i] = w_dcn[d * 2304 + i];
    __syncthreads();
    for (int i = t; i < 2304; i += 256) {
        const int k = i >> 8, c = i & 255;
        wT[k * 65536 + d * 256 + c] = f2bf(wl[c * 9 + k]);
    }
}

// ---------------- k0o: w_off [oc][c][3][3] -> wA [tap][oc_pad32][c] bf16 ----------------
__global__ __launch_bounds__(256) void k0_wo(const float* __restrict__ w_off, ushort* __restrict__ wA)
{
    const int e = blockIdx.x * 256 + threadIdx.x;   // 9*32*256 = 73728
    const int k = e >> 13, r = e & 8191;
    const int oc = r >> 8, c = r & 255;
    const float v = (oc < 27) ? w_off[(oc * 256 + c) * 9 + k] : 0.f;
    wA[e] = f2bf(v);
}

// ---------------- k1: offset conv MFMA, 8 waves (c-half split + LDS reduce) ----------------
__global__ __launch_bounds__(512) void k1_mfma(const ushort* __restrict__ xt,
    const ushort* __restrict__ wA, const float* __restrict__ b_off,
    float* __restrict__ offs, float* __restrict__ mk)
{
    const int bid = blockIdx.x;
    const int b = bid >> 6, h = bid & 63;
    const int t = threadIdx.x;
    const int lane = t & 63, wv = t >> 6;
    const int wq = wv & 3, chalf = wv >> 2;
    const int n = lane & 15, kq = lane >> 4;
    __shared__ float red[4][64][8];

    f32x4 acc0 = {0.f, 0.f, 0.f, 0.f}, acc1 = {0.f, 0.f, 0.f, 0.f};
    const ushort* xb = xt + ((size_t)b * HW) * 256;
    const int cb = chalf * 128;

    for (int k = 0; k < 9; ++k) {
        const int i = k / 3, j = k % 3;
        const int hh = h + 2 * (i - 1);
        if ((unsigned)hh >= 64u) continue;
        const int ww = wq * 16 + n + 2 * (j - 1);
        const bool vw = (unsigned)ww < 64u;
        const ushort* xrow  = xb + (hh * 64 + ww) * 256 + cb + kq * 8;
        const ushort* wrow0 = wA + (k * 32 + n) * 256 + cb + kq * 8;
        const ushort* wrow1 = wrow0 + 16 * 256;
#pragma unroll
        for (int c0 = 0; c0 < 128; c0 += 32) {
            short8 bfv = {0, 0, 0, 0, 0, 0, 0, 0};
            if (vw) bfv = *(const short8*)(xrow + c0);
            const short8 a0 = *(const short8*)(wrow0 + c0);
            const short8 a1 = *(const short8*)(wrow1 + c0);
            acc0 = __builtin_amdgcn_mfma_f32_16x16x32_bf16(a0, bfv, acc0, 0, 0, 0);
            acc1 = __builtin_amdgcn_mfma_f32_16x16x32_bf16(a1, bfv, acc1, 0, 0, 0);
        }
    }

    if (chalf == 1) {
#pragma unroll
        for (int r = 0; r < 4; ++r) {
            red[wq][lane][r]     = acc0[r];
            red[wq][lane][4 + r] = acc1[r];
        }
    }
    __syncthreads();
    if (chalf == 0) {
#pragma unroll
        for (int r = 0; r < 4; ++r) {
            acc0[r] += red[wq][lane][r];
            acc1[r] += red[wq][lane][4 + r];
        }
        const int hw = h * 64 + wq * 16 + n;
#pragma unroll
        for (int r = 0; r < 4; ++r) {
            {
                const int oc = kq * 4 + r;
                float v = acc0[r] + b_off[oc];
                v = fminf(fmaxf(v, -64.f), 64.f);
                offs[(b * 18 + oc) * HW + hw] = v;
            }
            {
                const int oc = 16 + kq * 4 + r;
                const float v = acc1[r] + b_off[min(oc, 26)];
                if (oc < 18) {
                    offs[(b * 18 + oc) * HW + hw] = fminf(fmaxf(v, -64.f), 64.f);
                } else if (oc < 27) {
                    mk[(b * 9 + (oc - 18)) * HW + hw] = 1.f / (1.f + expf(-v));
                }
            }
        }
    }
}

// ---------------- k2: fused sampling + MFMA GEMM ----------------
// block = (b,h); 512 threads = 8 waves; wave wv owns d [wv*32, wv*32+32), all 64 w.
// Per tap k: stage samp[64w][256c] bf16 (XOR-swizzled 16B granules), dbuf, 1 barrier/tap.
// A (wT) read direct from global (L2-resident).
__global__ __launch_bounds__(512) void k2_dcn(const ushort* __restrict__ xt, const ushort* __restrict__ wT,
    const float* __restrict__ offs, const float* __restrict__ mk, float* __restrict__ out)
{
    const int bid = blockIdx.x;
    const int wg = (bid & 7) * 32 + (bid >> 3);      // XCD-bijective swizzle
    const int b = wg >> 6, h = wg & 63;
    const int t = threadIdx.x;
    const int lane = t & 63, wv = t >> 6;
    const int n0 = lane & 15, kq = lane >> 4;

    __shared__ __align__(16) ushort S[2][16384];     // 2 x 64w x 256c bf16 = 64 KB

    const int sw = t >> 3;                           // staging: w 0..63
    const int so = (t & 7) * 4;                      // first 16B-granule (oct) of 4
    const int cbyte = (t & 7) * 64;                  // byte offset of 32-c slice

    const char* xc = (const char*)(xt + ((size_t)b * HW) * 256);
    const float* offb = offs + (size_t)b * 18 * HW + h * 64;
    const float* mkb  = mk   + (size_t)b *  9 * HW + h * 64;

    f32x4 acc[2][4];
#pragma unroll
    for (int dr = 0; dr < 2; ++dr)
#pragma unroll
        for (int nf = 0; nf < 4; ++nf) acc[dr][nf] = (f32x4){0.f, 0.f, 0.f, 0.f};

    auto stage = [&](int k, int pb) {
        const float dy = offb[(2 * k) * HW + sw];
        const float dx = offb[(2 * k + 1) * HW + sw];
        const float mval = mkb[k * HW + sw];
        const float py = (float)(h - 1 + k / 3) + dy;
        const float px = (float)(sw - 1 + k % 3) + dx;
        const float y0f = floorf(py), x0f = floorf(px);
        const float wy = py - y0f, wx = px - x0f;
        const int y0 = (int)y0f, x0 = (int)x0f;
        float w00 = (1.f - wy) * (1.f - wx) * mval, w01 = (1.f - wy) * wx * mval;
        float w10 = wy * (1.f - wx) * mval,         w11 = wy * wx * mval;
        const bool vy0 = (unsigned)y0 < 64u, vy1 = (unsigned)(y0 + 1) < 64u;
        const bool vx0 = (unsigned)x0 < 64u, vx1 = (unsigned)(x0 + 1) < 64u;
        if (!(vy0 && vx0)) w00 = 0.f;
        if (!(vy0 && vx1)) w01 = 0.f;
        if (!(vy1 && vx0)) w10 = 0.f;
        if (!(vy1 && vx1)) w11 = 0.f;
        const int y0c = min(max(y0, 0), 63), y1c = min(max(y0 + 1, 0), 63);
        const int x0c = min(max(x0, 0), 63), x1c = min(max(x0 + 1, 0), 63);
        const int o00 = (y0c * 64 + x0c) * 512, o01 = (y0c * 64 + x1c) * 512;
        const int o10 = (y1c * 64 + x0c) * 512, o11 = (y1c * 64 + x1c) * 512;
#pragma unroll
        for (int j = 0; j < 4; ++j) {
            const int cb2 = cbyte + j * 16;
            const short8 u00 = *(const short8*)(xc + o00 + cb2);
            const short8 u01 = *(const short8*)(xc + o01 + cb2);
            const short8 u10 = *(const short8*)(xc + o10 + cb2);
            const short8 u11 = *(const short8*)(xc + o11 + cb2);
            short8 r;
#pragma unroll
            for (int e = 0; e < 8; ++e) {
                const float v = w00 * bf2f((ushort)u00[e]) + w01 * bf2f((ushort)u01[e])
                              + w10 * bf2f((ushort)u10[e]) + w11 * bf2f((ushort)u11[e]);
                r[e] = (short)f2bf(v);
            }
            const int oct = so + j;
            *(short8*)&S[pb][sw * 256 + ((oct ^ (sw & 7)) << 3)] = r;
        }
    };

    auto gemm = [&](int k, int pb) {
        const ushort* Arow0 = wT + k * 65536 + (wv * 32 + n0) * 256 + kq * 8;
        const ushort* Arow1 = Arow0 + 16 * 256;
#pragma unroll
        for (int c0 = 0; c0 < 256; c0 += 32) {
            const short8 a0 = *(const short8*)(Arow0 + c0);
            const short8 a1 = *(const short8*)(Arow1 + c0);
#pragma unroll
            for (int nf = 0; nf < 4; ++nf) {
                const int w = nf * 16 + n0;
                const int oct = (c0 >> 3) + kq;
                const short8 bf = *(const short8*)&S[pb][w * 256 + ((oct ^ (w & 7)) << 3)];
                acc[0][nf] = __builtin_amdgcn_mfma_f32_16x16x32_bf16(a0, bf, acc[0][nf], 0, 0, 0);
                acc[1][nf] = __builtin_amdgcn_mfma_f32_16x16x32_bf16(a1, bf, acc[1][nf], 0, 0, 0);
            }
        }
    };

    stage(0, 0);
    __syncthreads();
#pragma unroll 1
    for (int k = 0; k < 9; ++k) {
        if (k < 8) stage(k + 1, (k + 1) & 1);
        gemm(k, k & 1);
        __syncthreads();
    }

    float* ob = out + ((size_t)b * 256) * HW + h * 64;
#pragma unroll
    for (int dr = 0; dr < 2; ++dr)
#pragma unroll
        for (int nf = 0; nf < 4; ++nf)
#pragma unroll
            for (int r = 0; r < 4; ++r) {
                const int d = wv * 32 + dr * 16 + kq * 4 + r;
                ob[(size_t)d * HW + nf * 16 + n0] = acc[dr][nf][r];
            }
}

// ---------------- k3: GroupNorm stats per (b,g) ----------------
__global__ __launch_bounds__(256) void k3_stats(const float* __restrict__ out, float* __restrict__ stats)
{
    const int bg = blockIdx.x;
    const float* p = out + (size_t)bg * 32768;
    float s = 0.f, s2 = 0.f;
    for (int i = threadIdx.x; i < 8192; i += 256) {
        float4 v = ((const float4*)p)[i];
        s  += v.x + v.y + v.z + v.w;
        s2 += v.x * v.x + v.y * v.y + v.z * v.z + v.w * v.w;
    }
    __shared__ float r1[256], r2[256];
    r1[threadIdx.x] = s; r2[threadIdx.x] = s2;
    __syncthreads();
    for (int st = 128; st > 0; st >>= 1) {
        if (threadIdx.x < st) {
            r1[threadIdx.x] += r1[threadIdx.x + st];
            r2[threadIdx.x] += r2[threadIdx.x + st];
        }
        __syncthreads();
    }
    if (threadIdx.x == 0) {
        const float mean = r1[0] / 32768.f;
        const float var  = r2[0] / 32768.f - mean * mean;
        stats[bg * 2]     = mean;
        stats[bg * 2 + 1] = rsqrtf(var + 1e-5f);
    }
}

// ---------------- k4: normalize + affine + SiLU ----------------
__global__ __launch_bounds__(256) void k4_gn(float* __restrict__ out,
    const float* __restrict__ stats, const float* __restrict__ gamma, const float* __restrict__ beta)
{
    const int i4 = blockIdx.x * 256 + threadIdx.x;
    const int elem = i4 << 2;
    const int b = elem >> 20;
    const int ch = (elem >> 12) & 255;
    const int g = ch >> 3;
    const float mean = stats[(b * 32 + g) * 2];
    const float rstd = stats[(b * 32 + g) * 2 + 1];
    const float ga = gamma[ch], be = beta[ch];
    float4 v = ((float4*)out)[i4];
    float vv[4] = {v.x, v.y, v.z, v.w};
#pragma unroll
    for (int j = 0; j < 4; ++j) {
        const float o = (vv[j] - mean) * rstd * ga + be;
        vv[j] = o / (1.f + expf(-o));
    }
    ((float4*)out)[i4] = make_float4(vv[0], vv[1], vv[2], vv[3]);
}

extern "C" void kernel_launch(void* const* d_in, const int* in_sizes, int n_in,
                              void* d_out, int out_size, void* d_ws, size_t ws_size,
                              hipStream_t stream)
{
    const float* x     = (const float*)d_in[0];
    const float* w_off = (const float*)d_in[1];
    const float* b_off = (const float*)d_in[2];
    const float* w_dcn = (const float*)d_in[3];
    const float* gamma = (const float*)d_in[4];
    const float* beta  = (const float*)d_in[5];
    float* out = (float*)d_out;

    // ws layout: xt bf16 (8 MB) | offs | mk | stats | wT bf16 | wA bf16
    ushort* xt    = (ushort*)d_ws;
    float*  offs  = (float*)d_ws + 2097152;
    float*  mk    = offs + 294912;
    float*  stats = mk + 147456;
    ushort* wT    = (ushort*)(stats + 256);
    ushort* wA    = wT + 589824;

    hipLaunchKernelGGL(k0_xt,    dim3(256),  dim3(256), 0, stream, x, xt);
    hipLaunchKernelGGL(k0_wt,    dim3(256),  dim3(256), 0, stream, w_dcn, wT);
    hipLaunchKernelGGL(k0_wo,    dim3(288),  dim3(256), 0, stream, w_off, wA);
    hipLaunchKernelGGL(k1_mfma,  dim3(256),  dim3(512), 0, stream, xt, wA, b_off, offs, mk);
    hipLaunchKernelGGL(k2_dcn,   dim3(256),  dim3(512), 0, stream, xt, wT, offs, mk, out);
    hipLaunchKernelGGL(k3_stats, dim3(128),  dim3(256), 0, stream, out, stats);
    hipLaunchKernelGGL(k4_gn,    dim3(4096), dim3(256), 0, stream, out, stats, gamma, beta);
}